// Round 4
// baseline (333.001 us; speedup 1.0000x reference)
//
#include <hip/hip_runtime.h>
#include <math.h>

typedef float fvec4 __attribute__((ext_vector_type(4)));  // native vector for nontemporal builtin

// Fused kernel:
//  Stage A (all 1536 blocks): spatial mean over H*W=4096 floats per (b,c,t)
//    row. One WAVE per row, 16 coalesced float4 nontemporal loads per lane,
//    8 rows per 512-thread block.
//  Stage B (last block only, via device-scope atomic counter): per-batch PCA
//    on means [3,512]. One wave per batch (8 waves = 8 batches), Gram
//    reduction by shuffle, analytic 3x3 eigensolve in double on lane 0,
//    broadcast, write out. Saves the second kernel launch.
__global__ __launch_bounds__(512) void fused_kernel(const float* __restrict__ x,
                                                    float* __restrict__ m,
                                                    unsigned int* __restrict__ counter,
                                                    float* __restrict__ out) {
    const int wave = threadIdx.x >> 6;             // 0..7
    const int lane = threadIdx.x & 63;
    const int row  = blockIdx.x * 8 + wave;        // 0..12287
    const fvec4* p = (const fvec4*)(x + (size_t)row * 4096);

    // 4096 floats = 1024 float4 per row / 64 lanes = 16 float4 per lane.
    fvec4 v[16];
#pragma unroll
    for (int k = 0; k < 16; ++k)
        v[k] = __builtin_nontemporal_load(&p[lane + 64 * k]);

    float s = 0.f;
#pragma unroll
    for (int k = 0; k < 16; ++k)
        s += (v[k].x + v[k].y) + (v[k].z + v[k].w);

    for (int off = 32; off; off >>= 1) s += __shfl_down(s, off, 64);
    if (lane == 0) m[row] = s * (1.0f / 4096.0f);

    // ---- last-block handoff (device-scope: per-XCD L2s are not coherent) ----
    __shared__ int sh_last;
    __syncthreads();
    if (threadIdx.x == 0) {
        __threadfence();                            // release: write back m stores
        unsigned old = atomicAdd(counter, 1u);      // device-scope by default
        sh_last = (old == (unsigned)(gridDim.x - 1));
    }
    __syncthreads();
    if (!sh_last) return;
    __threadfence();                                // acquire: invalidate stale caches

    // ---- Stage B: PCA. wave w handles batch b=w; lane owns 8 columns. ----
    const int b = wave;
    const float* X = m + b * 1536;                  // [3,512] means for batch b

    float c0v[8], c1v[8], c2v[8];
    float g0 = 0, g1 = 0, g2 = 0, g3 = 0, g4 = 0, g5 = 0;
#pragma unroll
    for (int k = 0; k < 8; ++k) {
        const int col = lane + 64 * k;              // coalesced
        const float x0 = X[col], x1 = X[512 + col], x2 = X[1024 + col];
        const float mu = (x0 + x1 + x2) * (1.0f / 3.0f);
        const float c0 = x0 - mu, c1 = x1 - mu, c2 = x2 - mu;
        c0v[k] = c0; c1v[k] = c1; c2v[k] = c2;
        g0 += c0 * c0; g1 += c0 * c1; g2 += c0 * c2;
        g3 += c1 * c1; g4 += c1 * c2; g5 += c2 * c2;
    }
    for (int off = 32; off; off >>= 1) {
        g0 += __shfl_down(g0, off, 64);
        g1 += __shfl_down(g1, off, 64);
        g2 += __shfl_down(g2, off, 64);
        g3 += __shfl_down(g3, off, 64);
        g4 += __shfl_down(g4, off, 64);
        g5 += __shfl_down(g5, off, 64);
    }

    float cf0 = 0.f, cf1 = 0.f, cf2 = 0.f;
    if (lane == 0) {
        const double a00 = g0, a01 = g1, a02 = g2;
        const double a11 = g3, a12 = g4, a22 = g5;

        // Analytic middle eigenvalue of symmetric 3x3 (trig method).
        const double q = (a00 + a11 + a22) / 3.0;
        const double b00 = a00 - q, b11 = a11 - q, b22 = a22 - q;
        const double p2 = b00 * b00 + b11 * b11 + b22 * b22
                        + 2.0 * (a01 * a01 + a02 * a02 + a12 * a12);
        double p = sqrt(p2 / 6.0);
        double l1;
        if (p < 1e-300) {
            l1 = q;
        } else {
            const double pinv = 1.0 / p;
            const double d00 = b00 * pinv, d11 = b11 * pinv, d22 = b22 * pinv;
            const double d01 = a01 * pinv, d02 = a02 * pinv, d12 = a12 * pinv;
            double r = 0.5 * (d00 * (d11 * d22 - d12 * d12)
                            - d01 * (d01 * d22 - d12 * d02)
                            + d02 * (d01 * d12 - d11 * d02));
            r = fmin(1.0, fmax(-1.0, r));
            const double phi = acos(r) / 3.0;
            const double l_max = q + 2.0 * p * cos(phi);
            const double l_min = q + 2.0 * p * cos(phi + 2.0943951023931953);
            l1 = 3.0 * q - l_max - l_min;
        }

        // Eigenvector via cross products of rows of (A - l1*I); pick largest.
        const double r0x = a00 - l1, r0y = a01,      r0z = a02;
        const double r1x = a01,      r1y = a11 - l1, r1z = a12;
        const double r2x = a02,      r2y = a12,      r2z = a22 - l1;

        double vax = r0y * r1z - r0z * r1y;
        double vay = r0z * r1x - r0x * r1z;
        double vaz = r0x * r1y - r0y * r1x;
        double vbx = r0y * r2z - r0z * r2y;
        double vby = r0z * r2x - r0x * r2z;
        double vbz = r0x * r2y - r0y * r2x;
        double vcx = r1y * r2z - r1z * r2y;
        double vcy = r1z * r2x - r1x * r2z;
        double vcz = r1x * r2y - r1y * r2x;

        const double na = vax * vax + vay * vay + vaz * vaz;
        const double nb = vbx * vbx + vby * vby + vbz * vbz;
        const double nc = vcx * vcx + vcy * vcy + vcz * vcz;

        double vx = vax, vy = vay, vz = vaz, n = na;
        if (nb > n) { vx = vbx; vy = vby; vz = vbz; n = nb; }
        if (nc > n) { vx = vcx; vy = vcy; vz = vcz; n = nc; }
        const double ninv = (n > 0.0) ? (1.0 / sqrt(n)) : 0.0;
        vx *= ninv; vy *= ninv; vz *= ninv;

        // svd_flip sign: sign of max-|.| component (first max wins).
        int idx = 0;
        double best = fabs(vx);
        if (fabs(vy) > best) { best = fabs(vy); idx = 1; }
        if (fabs(vz) > best) { best = fabs(vz); idx = 2; }
        const double comp = (idx == 0) ? vx : (idx == 1) ? vy : vz;
        const double sg = (comp >= 0.0) ? 1.0 : -1.0;

        // out[t] = sg * (u1 . Xc[:,t]) * sqrt(l1) / 2
        const double scale = sg * 0.5 * sqrt(fmax(l1, 0.0));
        cf0 = (float)(vx * scale);
        cf1 = (float)(vy * scale);
        cf2 = (float)(vz * scale);
    }
    cf0 = __shfl(cf0, 0, 64);
    cf1 = __shfl(cf1, 0, 64);
    cf2 = __shfl(cf2, 0, 64);

#pragma unroll
    for (int k = 0; k < 8; ++k)
        out[b * 512 + lane + 64 * k] = cf0 * c0v[k] + cf1 * c1v[k] + cf2 * c2v[k];
}

extern "C" void kernel_launch(void* const* d_in, const int* in_sizes, int n_in,
                              void* d_out, int out_size, void* d_ws, size_t ws_size,
                              hipStream_t stream) {
    const float* x = (const float*)d_in[0];   // [8, 3, 512, 64, 64] fp32
    float* out = (float*)d_out;               // [8, 512] fp32

    unsigned int* counter = (unsigned int*)d_ws;              // 4 B, must be 0
    float* m = (float*)((char*)d_ws + 1024);                  // [8,3,512] means

    hipMemsetAsync(d_ws, 0, 4, stream);       // zero the counter (capturable)

    const int ROWS = 8 * 3 * 512;             // 12288 -> 1536 blocks
    fused_kernel<<<ROWS / 8, 512, 0, stream>>>(x, m, counter, out);
}

// Round 5
// 253.600 us; speedup vs baseline: 1.3131x; 1.3131x over previous
//
#include <hip/hip_runtime.h>
#include <math.h>

typedef float fvec4 __attribute__((ext_vector_type(4)));  // native vector for nontemporal builtin

// Stage 1: spatial mean over H*W=4096 contiguous floats per (b,c,t) row.
// One WAVE (64 lanes) per row: no LDS, no __syncthreads. Each lane loads
// 16 float4s (coalesced: lane i reads float4 index lane + 64*k), giving
// 256 B of outstanding loads per lane. 512-thread blocks = 8 waves = 8
// rows/block -> 1536 blocks for 12288 rows.
// NOTE (R4 post-mortem): do NOT fuse stage 2 into this kernel's tail —
// carrying the PCA register state + per-block device fences cost +78 µs.
__global__ __launch_bounds__(512) void mean_kernel(const float* __restrict__ x,
                                                   float* __restrict__ m) {
    const int wave = threadIdx.x >> 6;             // 0..7
    const int lane = threadIdx.x & 63;
    const int row  = blockIdx.x * 8 + wave;        // 0..12287
    const fvec4* p = (const fvec4*)(x + (size_t)row * 4096);

    // 4096 floats = 1024 float4 per row / 64 lanes = 16 float4 per lane.
    fvec4 v[16];
#pragma unroll
    for (int k = 0; k < 16; ++k)
        v[k] = __builtin_nontemporal_load(&p[lane + 64 * k]);

    float s = 0.f;
#pragma unroll
    for (int k = 0; k < 16; ++k)
        s += (v[k].x + v[k].y) + (v[k].z + v[k].w);

    // wave-level reduce (width 64)
    for (int off = 32; off; off >>= 1) s += __shfl_down(s, off, 64);

    if (lane == 0) m[row] = s * (1.0f / 4096.0f);
}

// Stage 2: per-batch PCA on X[3,512]. One block per batch, 512 threads
// (thread t owns column t). Gram reduce -> 3x3 symmetric eigensolve
// (double, analytic) on thread 0 -> broadcast coefficients -> write.
__global__ __launch_bounds__(512) void pca_kernel(const float* __restrict__ m,
                                                  float* __restrict__ out) {
    const int b = blockIdx.x;
    const int t = threadIdx.x;                      // 0..511
    const float* X = m + b * 3 * 512;

    const float x0 = X[t], x1 = X[512 + t], x2 = X[1024 + t];
    const float mu = (x0 + x1 + x2) * (1.0f / 3.0f);
    const float c0 = x0 - mu, c1 = x1 - mu, c2 = x2 - mu;

    float g[6] = { c0 * c0, c0 * c1, c0 * c2, c1 * c1, c1 * c2, c2 * c2 };

    __shared__ float red[8][6];
#pragma unroll
    for (int j = 0; j < 6; ++j) {
        float v = g[j];
        for (int off = 32; off; off >>= 1) v += __shfl_down(v, off, 64);
        g[j] = v;
    }
    const int wave = t >> 6, lane = t & 63;
    if (lane == 0) {
#pragma unroll
        for (int j = 0; j < 6; ++j) red[wave][j] = g[j];
    }
    __syncthreads();

    __shared__ float coef[3];
    if (t == 0) {
        double G[6] = {0, 0, 0, 0, 0, 0};
        for (int w = 0; w < 8; ++w)
            for (int j = 0; j < 6; ++j) G[j] += (double)red[w][j];
        const double a00 = G[0], a01 = G[1], a02 = G[2];
        const double a11 = G[3], a12 = G[4], a22 = G[5];

        // Analytic eigenvalues of symmetric 3x3 (trig method).
        const double q = (a00 + a11 + a22) / 3.0;
        const double b00 = a00 - q, b11 = a11 - q, b22 = a22 - q;
        const double p2 = b00 * b00 + b11 * b11 + b22 * b22
                        + 2.0 * (a01 * a01 + a02 * a02 + a12 * a12);
        double p = sqrt(p2 / 6.0);
        double l1;  // middle eigenvalue (second singular value squared)
        if (p < 1e-300) {
            l1 = q;
        } else {
            const double pinv = 1.0 / p;
            const double d00 = b00 * pinv, d11 = b11 * pinv, d22 = b22 * pinv;
            const double d01 = a01 * pinv, d02 = a02 * pinv, d12 = a12 * pinv;
            double r = 0.5 * (d00 * (d11 * d22 - d12 * d12)
                            - d01 * (d01 * d22 - d12 * d02)
                            + d02 * (d01 * d12 - d11 * d02));
            r = fmin(1.0, fmax(-1.0, r));
            const double phi = acos(r) / 3.0;
            const double l_max = q + 2.0 * p * cos(phi);
            const double l_min = q + 2.0 * p * cos(phi + 2.0943951023931953);  // +2pi/3
            l1 = 3.0 * q - l_max - l_min;
        }

        // Eigenvector for l1 via cross products of rows of (A - l1*I).
        const double r0x = a00 - l1, r0y = a01,      r0z = a02;
        const double r1x = a01,      r1y = a11 - l1, r1z = a12;
        const double r2x = a02,      r2y = a12,      r2z = a22 - l1;

        double vax = r0y * r1z - r0z * r1y;
        double vay = r0z * r1x - r0x * r1z;
        double vaz = r0x * r1y - r0y * r1x;
        double vbx = r0y * r2z - r0z * r2y;
        double vby = r0z * r2x - r0x * r2z;
        double vbz = r0x * r2y - r0y * r2x;
        double vcx = r1y * r2z - r1z * r2y;
        double vcy = r1z * r2x - r1x * r2z;
        double vcz = r1x * r2y - r1y * r2x;

        const double na = vax * vax + vay * vay + vaz * vaz;
        const double nb = vbx * vbx + vby * vby + vbz * vbz;
        const double nc = vcx * vcx + vcy * vcy + vcz * vcz;

        double vx = vax, vy = vay, vz = vaz, n = na;
        if (nb > n) { vx = vbx; vy = vby; vz = vbz; n = nb; }
        if (nc > n) { vx = vcx; vy = vcy; vz = vcz; n = nc; }
        const double ninv = (n > 0.0) ? (1.0 / sqrt(n)) : 0.0;
        vx *= ninv; vy *= ninv; vz *= ninv;

        // svd_flip sign: sign of the max-|.| component of u1 (first max).
        int idx = 0;
        double best = fabs(vx);
        if (fabs(vy) > best) { best = fabs(vy); idx = 1; }
        if (fabs(vz) > best) { best = fabs(vz); idx = 2; }
        const double comp = (idx == 0) ? vx : (idx == 1) ? vy : vz;
        const double s = (comp >= 0.0) ? 1.0 : -1.0;

        // out[t] = s * (u1 . Xc[:,t]) * sqrt(l1) / 2
        const double scale = s * 0.5 * sqrt(fmax(l1, 0.0));
        coef[0] = (float)(vx * scale);
        coef[1] = (float)(vy * scale);
        coef[2] = (float)(vz * scale);
    }
    __syncthreads();

    out[b * 512 + t] = coef[0] * c0 + coef[1] * c1 + coef[2] * c2;
}

extern "C" void kernel_launch(void* const* d_in, const int* in_sizes, int n_in,
                              void* d_out, int out_size, void* d_ws, size_t ws_size,
                              hipStream_t stream) {
    const float* x = (const float*)d_in[0];   // [8, 3, 512, 64, 64] fp32
    float* out = (float*)d_out;               // [8, 512] fp32
    float* m = (float*)d_ws;                  // [8, 3, 512] spatial means (49 KB)

    const int ROWS = 8 * 3 * 512;             // 12288
    mean_kernel<<<ROWS / 8, 512, 0, stream>>>(x, m);
    pca_kernel<<<8, 512, 0, stream>>>(m, out);
}